// Round 2
// baseline (170.118 us; speedup 1.0000x reference)
//
#include <hip/hip_runtime.h>

// HandcraftedPodExtractor: 3D cell binning + normalized feature vector.
// Input  x: (64, 65536, 6) fp32  [pos(3) | ori(3)] interleaved per point.
// Output  : (64, 640) fp32.
//
// R12 = R10 (plain int32 LDS atomics) + full-32-bank interleaved layout.
// Post-mortem R11: u64 packing (half the DS instructions) was NEUTRAL ->
// DS atomic phase is bank-cycle bound, not issue bound. Both R10 and R11
// layouts had per-cell stride ≡ 0 (mod 32 words), so a single atomic
// instruction's 64 lanes covered only 16 banks (4 touches/bank = 1.58x
// regime per m136). Minimum for u32 is 2 touches/bank ("free" regime).
//
// New layout: cells paired into 32 groups; word addr =
//   (cell>>1)*320 + j*32 + 2*kk + (cell&1),  kk = k ^ (cell&15)
// For fixed j: bank = 2*kk + (cell&1) -> covers all 32 banks (even banks
// from even cells, odd from odd, kk spreads 16 slots each). Expected
// conflict 4-way -> 2-way, halving the atomic bank-cycle phase.
// Total LDS unchanged: 32 groups * 10 fields * 32 slots * 4 B = 40960 B
// -> 4 blocks/CU preserved (the R6/R9 lesson: occupancy is king here).
//
// History: R9 last-block fusion regressed (+26 us: finalize tail raised
// k_bin VGPR -> lost 4 blk/CU); R7/R8 cooperative fusion regressed
// (grid.sync across 8 non-coherent XCD L2s); R11 u64 packing neutral.
//
// Ceiling accounting: ~107 us harness traffic in timed window (402 MB
// ws-poison @ 59 us + input restore) + k_bbox ~16 (HBM ceiling for the
// 100 MB read) + k_bin (100 MB re-read + atomics) + k_final ~4 + gaps.
//
// Fixed-point scales (R3): offsets x2^18, cov x2^12; out err ~1e-4 << 5.9e-3.
// Overflow: per (cell,copy) slot <= 256 adds of |v|<2^18ish -> < 2^27;
// 16-copy sum < 2^31. Signed wraparound exact mod 2^32 either way.
//
// ws layout:
//   [0,    4096)           : part_max[B*16] as uint bits (nonneg floats)
//   [4096, 4096 + 327680)  : acc[B][640] int64

#define BATCH 64
#define NPTS 65536
#define FEAT 640          // 64 cells * 10 values
#define COPIES 16         // replicated histogram slots per (cell, field)
#define HWORDS 10240      // 32 groups * 10 fields * 32 slots
#define S_OFF 262144.0f   // 2^18
#define S_COV 4096.0f     // 2^12

__device__ __forceinline__ void bin_point(int* h, int k,
                                          float px, float py, float pz,
                                          float ox, float oy, float oz,
                                          float bmax, float inv_thick) {
    float sx = (px + bmax) * inv_thick;
    float sy = (py + bmax) * inv_thick;
    float sz = (pz + bmax) * inv_thick;
    int cx = (int)(sx * 4.0f); cx = cx < 0 ? 0 : (cx > 3 ? 3 : cx);
    int cy = (int)(sy * 4.0f); cy = cy < 0 ? 0 : (cy > 3 ? 3 : cy);
    int cz = (int)(sz * 4.0f); cz = cz < 0 ? 0 : (cz > 3 ? 3 : cz);
    int cell = (cx * 4 + cy) * 4 + cz;
    float offx = sx - (cx * 0.25f + 0.125f);
    float offy = sy - (cy * 0.25f + 0.125f);
    float offz = sz - (cz * 0.25f + 0.125f);
    int kk = k ^ (cell & 15);
    // word addr: group*320 + j*32 + slot; slot = 2*kk + (cell&1)
    // -> bank for fixed j = (2*kk + (cell&1)) mod 32: all 32 banks.
    int a = (cell >> 1) * 320 + 2 * kk + (cell & 1);
    atomicAdd(&h[a + 0 * 32], 1);
    atomicAdd(&h[a + 1 * 32], __float2int_rn(offx * S_OFF));
    atomicAdd(&h[a + 2 * 32], __float2int_rn(offy * S_OFF));
    atomicAdd(&h[a + 3 * 32], __float2int_rn(offz * S_OFF));
    atomicAdd(&h[a + 4 * 32], __float2int_rn(ox * ox * S_COV));
    atomicAdd(&h[a + 5 * 32], __float2int_rn(ox * oy * S_COV));
    atomicAdd(&h[a + 6 * 32], __float2int_rn(ox * oz * S_COV));
    atomicAdd(&h[a + 7 * 32], __float2int_rn(oy * oy * S_COV));
    atomicAdd(&h[a + 8 * 32], __float2int_rn(oy * oz * S_COV));
    atomicAdd(&h[a + 9 * 32], __float2int_rn(oz * oz * S_COV));
}

// Pass 1: per-batch max|pos| -> partial maxes; also zero-init acc.
// grid (16, B) x 256.
__global__ __launch_bounds__(256) void k_bbox(const float* __restrict__ x,
                                              unsigned int* __restrict__ part,
                                              unsigned long long* __restrict__ acc) {
    int b = blockIdx.y;
    int fb = b * 16 + blockIdx.x;             // flat block id 0..1023
    if (threadIdx.x < 40) acc[fb * 40 + threadIdx.x] = 0ULL;

    const float4* F = (const float4*)(x + (size_t)b * NPTS * 6);
    int tid = blockIdx.x * 256 + threadIdx.x;   // 4096 threads per batch
    int tm = tid % 3;
    float m = 0.0f;
    #pragma unroll
    for (int o = 0; o < 2; ++o) {
        #pragma unroll
        for (int u = 0; u < 12; ++u) {
            int it = o * 12 + u;
            float4 v = F[tid + it * 4096];      // unit stride across lanes
            int mm = tm + (u % 3);              // (tm + it) % 3; 12 % 3 == 0
            mm = mm >= 3 ? mm - 3 : mm;
            float ax = fabsf(v.x), ay = fabsf(v.y), az = fabsf(v.z), aw = fabsf(v.w);
            float c0 = fmaxf(fmaxf(ax, ay), az);
            float c1 = fmaxf(az, aw);
            float cand = mm == 0 ? c0 : (mm == 1 ? c1 : ax);
            m = fmaxf(m, cand);
        }
    }
    for (int off = 32; off > 0; off >>= 1) m = fmaxf(m, __shfl_down(m, off, 64));
    __shared__ float s[4];
    if ((threadIdx.x & 63) == 0) s[threadIdx.x >> 6] = m;
    __syncthreads();
    if (threadIdx.x == 0) {
        m = fmaxf(fmaxf(s[0], s[1]), fmaxf(s[2], s[3]));
        part[fb] = __float_as_uint(m);          // plain store, no init needed
    }
}

// Pass 2: int32 histogram into 32-bank interleaved LDS slots, i64 flush.
// grid (16, B) x 256. LDS = 40960 B -> 4 blocks/CU, no dispatch tail.
__global__ __launch_bounds__(256) void k_bin(const float* __restrict__ x,
                                             const unsigned int* __restrict__ part,
                                             unsigned long long* __restrict__ acc) {
    __shared__ int h[HWORDS];                   // 40960 B
    for (int i = threadIdx.x; i < HWORDS; i += 256) h[i] = 0;
    int b = blockIdx.y;
    // reduce the 16 partial maxes (uint compare == float compare for >=0)
    unsigned int um = 0u;
    #pragma unroll
    for (int p = 0; p < 16; ++p) um = um > part[b * 16 + p] ? um : part[b * 16 + p];
    float bmax = __uint_as_float(um);
    float thick = fmaxf(2.0f * bmax, 1e-5f);
    float inv_thick = 1.0f / thick;
    __syncthreads();

    const float4* base = (const float4*)(x + (size_t)b * NPTS * 6);
    int tid = blockIdx.x * 256 + threadIdx.x;   // 4096 threads per batch
    int k = threadIdx.x & (COPIES - 1);
    #pragma unroll
    for (int it = 0; it < 8; ++it) {
        int i = tid + it * 4096;
        float4 f0 = base[3 * i + 0];
        float4 f1 = base[3 * i + 1];
        float4 f2 = base[3 * i + 2];
        bin_point(h, k, f0.x, f0.y, f0.z, f0.w, f1.x, f1.y, bmax, inv_thick);
        bin_point(h, k, f1.z, f1.w, f2.x, f2.y, f2.z, f2.w, bmax, inv_thick);
    }
    __syncthreads();
    for (int v = threadIdx.x; v < FEAT; v += 256) {
        int cell = v / 10, j = v - cell * 10;
        int base_w = (cell >> 1) * 320 + j * 32 + (cell & 1);
        long long sum = 0;
        #pragma unroll
        for (int c = 0; c < COPIES; ++c) sum += (long long)h[base_w + 2 * c];
        atomicAdd(&acc[b * FEAT + v], (unsigned long long)sum); // native int64
    }
}

// Pass 3: features + L2 normalize. grid B x 640 (one thread per feature).
__global__ __launch_bounds__(640) void k_final(const unsigned long long* __restrict__ acc,
                                               float* __restrict__ out) {
    int b = blockIdx.x;
    int t = threadIdx.x;           // 0..639
    int cell = t / 10, j = t - cell * 10;
    long long ni = (long long)acc[b * FEAT + cell * 10];   // exact count
    long long vi = (long long)acc[b * FEAT + t];
    float n = (float)ni;
    float fc = fmaxf(n, 1.0f);
    float up = 1.0f / sqrtf(fc);
    float val;
    if (j == 0)      val = 0.001f * n * up;
    else if (j < 4)  val = ((float)vi * (1.0f / S_OFF)) * up;
    else             val = ((float)vi * (1.0f / S_COV)) / fc;

    __shared__ float red[12];
    float s = val * val;
    for (int off = 32; off > 0; off >>= 1) s += __shfl_down(s, off, 64);
    if ((t & 63) == 0) red[t >> 6] = s;
    __syncthreads();
    if (t == 0) {
        float tot = 0.0f;
        #pragma unroll
        for (int w = 0; w < 10; ++w) tot += red[w];
        red[10] = fmaxf(sqrtf(tot), 1e-12f);
    }
    __syncthreads();
    out[b * FEAT + t] = val / red[10];
}

extern "C" void kernel_launch(void* const* d_in, const int* in_sizes, int n_in,
                              void* d_out, int out_size, void* d_ws, size_t ws_size,
                              hipStream_t stream) {
    const float* x = (const float*)d_in[0];
    float* out = (float*)d_out;
    unsigned int* part = (unsigned int*)d_ws;
    unsigned long long* acc = (unsigned long long*)((char*)d_ws + 4096);

    dim3 grid(16, BATCH);
    k_bbox<<<grid, 256, 0, stream>>>(x, part, acc);
    k_bin<<<grid, 256, 0, stream>>>(x, part, acc);
    k_final<<<BATCH, 640, 0, stream>>>(acc, out);
}

// Round 3
// 163.506 us; speedup vs baseline: 1.0404x; 1.0404x over previous
//
#include <hip/hip_runtime.h>

// HandcraftedPodExtractor: 3D cell binning + normalized feature vector.
// Input  x: (64, 65536, 6) fp32  [pos(3) | ori(3)] interleaved per point.
// Output  : (64, 640) fp32.
//
// R13 = exact R6/R10 hot path (measured best 161.4/162.2 us) + tail-only
// change: k_bin flushes per-block PARTIAL sums with plain u64 stores
// (1024 x 640, 5.2 MB, full overwrite each iter -> poison-safe) instead
// of 655K contended global atomicAdds; k_final sums the 16 partials
// (5.2 MB extra read at L2/L3 speed ~ 0.2 us). k_bbox no longer zeroes acc.
//
// Post-mortems driving this:
//  R11 (u64-packed DS atomics, half the instructions): NEUTRAL/worse.
//  R12 (32-bank interleave, half the bank pressure):   WORSE (+5 us).
//  => The LDS-atomic phase is NOT k_bin's critical path; it is hidden
//  under the 100 MB stream. Only the memory floor + tail remain. Do not
//  touch the hot loop again.
//  R9 (fused finalize): VGPR raise -> lost 4 blk/CU. R7/R8 (grid.sync
//  fusion): device-scope spin across 8 non-coherent XCD L2s, regressed.
//
// Ceiling accounting: ~107 us harness traffic in the timed window
// (402 MB ws-poison fills @ ~59 us each + input restore) + k_bbox ~16
// (100 MB @ HBM ceiling) + k_bin ~20 (100 MB re-read, L3-assisted, DS
// hidden) + k_final ~4 + gaps ~6-10 => ~157-162 us structural floor.
//
// Fixed-point scales (R3): offsets x2^18, cov x2^12; out err ~1e-4 << 5.9e-3.
// Bank swizzle (R6): kk = k ^ (cell & 15) on stride-16 copies; LDS
// 640*16*4 = 40960 B exactly -> 4 blocks/CU (all 1024 blocks co-resident).
//
// ws layout:
//   [0,    4096)             : part_max[B*16] as uint bits (nonneg floats)
//   [4096, 4096 + 5242880)   : partials[1024][640] int64 (per-block sums)

#define BATCH 64
#define NPTS 65536
#define FEAT 640          // 64 cells * 10 values
#define COPIES 16         // replicated LDS histograms, XOR-swizzled
#define CSTRIDE 16        // copy stride (no pad; swizzle handles banks)
#define S_OFF 262144.0f   // 2^18
#define S_COV 4096.0f     // 2^12

__device__ __forceinline__ void bin_point(int* h, int k,
                                          float px, float py, float pz,
                                          float ox, float oy, float oz,
                                          float bmax, float inv_thick) {
    float sx = (px + bmax) * inv_thick;
    float sy = (py + bmax) * inv_thick;
    float sz = (pz + bmax) * inv_thick;
    int cx = (int)(sx * 4.0f); cx = cx < 0 ? 0 : (cx > 3 ? 3 : cx);
    int cy = (int)(sy * 4.0f); cy = cy < 0 ? 0 : (cy > 3 ? 3 : cy);
    int cz = (int)(sz * 4.0f); cz = cz < 0 ? 0 : (cz > 3 ? 3 : cz);
    int cell = (cx * 4 + cy) * 4 + cz;
    float offx = sx - (cx * 0.25f + 0.125f);
    float offy = sy - (cy * 0.25f + 0.125f);
    float offz = sz - (cz * 0.25f + 0.125f);
    int kk = k ^ (cell & 15);               // bank de-alias across cells
    int a = cell * (10 * CSTRIDE) + kk;
    atomicAdd(&h[a + 0 * CSTRIDE], 1);
    atomicAdd(&h[a + 1 * CSTRIDE], __float2int_rn(offx * S_OFF));
    atomicAdd(&h[a + 2 * CSTRIDE], __float2int_rn(offy * S_OFF));
    atomicAdd(&h[a + 3 * CSTRIDE], __float2int_rn(offz * S_OFF));
    atomicAdd(&h[a + 4 * CSTRIDE], __float2int_rn(ox * ox * S_COV));
    atomicAdd(&h[a + 5 * CSTRIDE], __float2int_rn(ox * oy * S_COV));
    atomicAdd(&h[a + 6 * CSTRIDE], __float2int_rn(ox * oz * S_COV));
    atomicAdd(&h[a + 7 * CSTRIDE], __float2int_rn(oy * oy * S_COV));
    atomicAdd(&h[a + 8 * CSTRIDE], __float2int_rn(oy * oz * S_COV));
    atomicAdd(&h[a + 9 * CSTRIDE], __float2int_rn(oz * oz * S_COV));
}

// Pass 1: per-batch max|pos| -> partial maxes. grid (16, B) x 256.
__global__ __launch_bounds__(256) void k_bbox(const float* __restrict__ x,
                                              unsigned int* __restrict__ part) {
    int b = blockIdx.y;
    int fb = b * 16 + blockIdx.x;             // flat block id 0..1023

    const float4* F = (const float4*)(x + (size_t)b * NPTS * 6);
    int tid = blockIdx.x * 256 + threadIdx.x;   // 4096 threads per batch
    int tm = tid % 3;
    float m = 0.0f;
    #pragma unroll
    for (int o = 0; o < 2; ++o) {
        #pragma unroll
        for (int u = 0; u < 12; ++u) {
            int it = o * 12 + u;
            float4 v = F[tid + it * 4096];      // unit stride across lanes
            int mm = tm + (u % 3);              // (tm + it) % 3; 12 % 3 == 0
            mm = mm >= 3 ? mm - 3 : mm;
            float ax = fabsf(v.x), ay = fabsf(v.y), az = fabsf(v.z), aw = fabsf(v.w);
            float c0 = fmaxf(fmaxf(ax, ay), az);
            float c1 = fmaxf(az, aw);
            float cand = mm == 0 ? c0 : (mm == 1 ? c1 : ax);
            m = fmaxf(m, cand);
        }
    }
    for (int off = 32; off > 0; off >>= 1) m = fmaxf(m, __shfl_down(m, off, 64));
    __shared__ float s[4];
    if ((threadIdx.x & 63) == 0) s[threadIdx.x >> 6] = m;
    __syncthreads();
    if (threadIdx.x == 0) {
        m = fmaxf(fmaxf(s[0], s[1]), fmaxf(s[2], s[3]));
        part[fb] = __float_as_uint(m);          // plain store, no init needed
    }
}

// Pass 2: int32 histogram into 16 XOR-swizzled LDS copies; plain-store
// per-block i64 partials (no global atomics, poison-safe full overwrite).
// grid (16, B) x 256. LDS = 40960 B -> 4 blocks/CU, no dispatch tail.
__global__ __launch_bounds__(256) void k_bin(const float* __restrict__ x,
                                             const unsigned int* __restrict__ part,
                                             unsigned long long* __restrict__ partials) {
    __shared__ int h[FEAT * CSTRIDE];
    for (int i = threadIdx.x; i < FEAT * CSTRIDE; i += 256) h[i] = 0;
    int b = blockIdx.y;
    int fb = b * 16 + blockIdx.x;
    // reduce the 16 partial maxes (uint compare == float compare for >=0)
    unsigned int um = 0u;
    #pragma unroll
    for (int p = 0; p < 16; ++p) um = um > part[b * 16 + p] ? um : part[b * 16 + p];
    float bmax = __uint_as_float(um);
    float thick = fmaxf(2.0f * bmax, 1e-5f);
    float inv_thick = 1.0f / thick;
    __syncthreads();

    const float4* base = (const float4*)(x + (size_t)b * NPTS * 6);
    int tid = blockIdx.x * 256 + threadIdx.x;   // 4096 threads per batch
    int k = threadIdx.x & (COPIES - 1);
    #pragma unroll
    for (int it = 0; it < 8; ++it) {
        int i = tid + it * 4096;
        float4 f0 = base[3 * i + 0];
        float4 f1 = base[3 * i + 1];
        float4 f2 = base[3 * i + 2];
        bin_point(h, k, f0.x, f0.y, f0.z, f0.w, f1.x, f1.y, bmax, inv_thick);
        bin_point(h, k, f1.z, f1.w, f2.x, f2.y, f2.z, f2.w, bmax, inv_thick);
    }
    __syncthreads();
    unsigned long long* my = partials + (size_t)fb * FEAT;
    for (int v = threadIdx.x; v < FEAT; v += 256) {
        long long sum = 0;
        #pragma unroll
        for (int c = 0; c < COPIES; ++c) sum += (long long)h[v * CSTRIDE + c];
        my[v] = (unsigned long long)sum;        // plain store, coalesced
    }
}

// Pass 3: sum 16 block-partials, features + L2 normalize.
// grid B x 640 (one thread per feature).
__global__ __launch_bounds__(640) void k_final(const unsigned long long* __restrict__ partials,
                                               float* __restrict__ out) {
    int b = blockIdx.x;
    int t = threadIdx.x;           // 0..639
    int cell = t / 10, j = t - cell * 10;

    long long s64 = 0;
    #pragma unroll
    for (int p = 0; p < 16; ++p)
        s64 += (long long)partials[((size_t)b * 16 + p) * FEAT + t];

    __shared__ long long sums[FEAT];   // 5120 B
    sums[t] = s64;
    __syncthreads();

    long long ni = sums[cell * 10];    // exact count for this cell
    long long vi = s64;
    float n = (float)ni;
    float fc = fmaxf(n, 1.0f);
    float up = 1.0f / sqrtf(fc);
    float val;
    if (j == 0)      val = 0.001f * n * up;
    else if (j < 4)  val = ((float)vi * (1.0f / S_OFF)) * up;
    else             val = ((float)vi * (1.0f / S_COV)) / fc;

    __shared__ float red[12];
    float s = val * val;
    for (int off = 32; off > 0; off >>= 1) s += __shfl_down(s, off, 64);
    if ((t & 63) == 0) red[t >> 6] = s;
    __syncthreads();
    if (t == 0) {
        float tot = 0.0f;
        #pragma unroll
        for (int w = 0; w < 10; ++w) tot += red[w];
        red[10] = fmaxf(sqrtf(tot), 1e-12f);
    }
    __syncthreads();
    out[b * FEAT + t] = val / red[10];
}

extern "C" void kernel_launch(void* const* d_in, const int* in_sizes, int n_in,
                              void* d_out, int out_size, void* d_ws, size_t ws_size,
                              hipStream_t stream) {
    const float* x = (const float*)d_in[0];
    float* out = (float*)d_out;
    unsigned int* part = (unsigned int*)d_ws;
    unsigned long long* partials = (unsigned long long*)((char*)d_ws + 4096);

    dim3 grid(16, BATCH);
    k_bbox<<<grid, 256, 0, stream>>>(x, part);
    k_bin<<<grid, 256, 0, stream>>>(x, part, partials);
    k_final<<<BATCH, 640, 0, stream>>>(partials, out);
}